// Round 4
// baseline (304.279 us; speedup 1.0000x reference)
//
#include <hip/hip_runtime.h>
#include <stdint.h>

typedef __attribute__((ext_vector_type(8))) __bf16 bf16x8;
typedef __attribute__((ext_vector_type(4))) short short4v;
typedef __attribute__((ext_vector_type(4))) float f32x4;

#if __has_builtin(__builtin_amdgcn_exp2f)
#define EXP2(x) __builtin_amdgcn_exp2f(x)
#else
#define EXP2(x) exp2f(x)
#endif

// ---------- helpers ----------
__device__ __forceinline__ short f2bf(float f) {
  union { float f; uint32_t u; } v; v.f = f;
  uint32_t r = (v.u + 0x7fffu + ((v.u >> 16) & 1u)) >> 16;  // RNE
  return (short)(uint16_t)r;
}

// pack two fp32 -> two bf16 in one dword (RNE via hw bf16 cvt)
__device__ __forceinline__ uint32_t pk2bf(float a, float b) {
  union { __bf16 h; uint16_t u; } x, y;
  x.h = (__bf16)a; y.h = (__bf16)b;
  return (uint32_t)x.u | ((uint32_t)y.u << 16);
}

// async global->LDS, 16B per lane; lds base must be wave-uniform, HW writes lane i at base+16*i
__device__ __forceinline__ void gl2lds16(const void* g, const void* lds) {
  __builtin_amdgcn_global_load_lds(
      (const __attribute__((address_space(1))) void*)(uintptr_t)g,
      (__attribute__((address_space(3))) void*)(uint32_t)(uintptr_t)lds,
      16, 0, 0);
}

__device__ __forceinline__ bf16x8 frag8(const short* p) {
  return *(const bf16x8*)(const void*)p;
}

// ---------- kernel 1: fp32 -> bf16 for x, W_qkv, W_out ----------
__global__ void convert3_k(const float* __restrict__ s0, short* __restrict__ d0, int n0,
                           const float* __restrict__ s1, short* __restrict__ d1, int n1,
                           const float* __restrict__ s2, short* __restrict__ d2, int n2) {
  int i = blockIdx.x * blockDim.x + threadIdx.x;  // float4 units
  int t0 = n0 >> 2, t1 = t0 + (n1 >> 2), t2 = t1 + (n2 >> 2);
  const float* s; short* d; int off;
  if (i < t0) { s = s0; d = d0; off = i; }
  else if (i < t1) { s = s1; d = d1; off = i - t0; }
  else if (i < t2) { s = s2; d = d2; off = i - t1; }
  else return;
  float4 v = ((const float4*)s)[off];
  short4v o;
  o.x = f2bf(v.x); o.y = f2bf(v.y); o.z = f2bf(v.z); o.w = f2bf(v.w);
  *(short4v*)(d + off * 4) = o;
}

// ---------- kernel 2: RoPE tables [2048][32] + float mask table ----------
__global__ void rope_tab_k(float* __restrict__ cosT, float* __restrict__ sinT,
                           const unsigned char* __restrict__ mask, float* __restrict__ maskf) {
  int i = blockIdx.x * blockDim.x + threadIdx.x;  // 65536
  int pos = i >> 5, j = i & 31;
  float invf = exp2f(-(float)j * (8.965784284662087f / 32.0f));
  float ang = (float)pos * invf;
  float s, c;
  sincosf(ang, &s, &c);
  cosT[i] = c; sinT[i] = s;
  if (i < 8192) maskf[i] = mask[i] ? -1e30f : 0.0f;
}

// ---------- kernel 3/5: C[M,N] = A[M,K] * B[N,K]^T (+bias), bf16 in, MFMA ----------
// Double-buffered LDS staging, ONE barrier per k-iter: loads for tile k+1 issue at the
// top of iter k, so the vmcnt drain at the next barrier sits a full compute-body later.
// LDS rows are 64B = 4x16B chunks, XOR-swizzled to break 64B-stride bank aliasing.
// EPI==0: fp32 C + bias.  EPI==1: bias + RoPE + scatter Qb/Kb (bh,pos,d) and Vt (bh,d,pos).
// Q additionally scaled by 0.125*log2(e) so attention scores are ready for exp2.
template <int EPI>
__global__ __launch_bounds__(256, 3)
void gemm_bt_k(const short* __restrict__ A, const short* __restrict__ Bm,
               const float* __restrict__ bias, int N, int K,
               float* __restrict__ Cout,
               const float* __restrict__ cosT, const float* __restrict__ sinT,
               short* __restrict__ Qb, short* __restrict__ Kb, short* __restrict__ Vt) {
  __shared__ short As[2][128 * 32];
  __shared__ short Bs[2][128 * 32];
  const int tid = threadIdx.x;
  const int lane = tid & 63;
  const int w = tid >> 6;
  const int g = lane >> 4, l15 = lane & 15;
  const int wm = (w >> 1) * 64, wn = (w & 1) * 64;
  const int bm = blockIdx.x, bn = blockIdx.y;

  const int rseg = lane >> 2;
  const int cofs = ((lane & 3) ^ ((lane >> 3) & 3)) * 8;
  const int sA0 = w, sA1 = w + 4;
  const int arow0 = (bm * 128 + sA0 * 16 + rseg) * K;
  const int arow1 = (bm * 128 + sA1 * 16 + rseg) * K;
  const int brow0 = (bn * 128 + sA0 * 16 + rseg) * K;
  const int brow1 = (bn * 128 + sA1 * 16 + rseg) * K;

  const int rsw = (l15 >> 1) & 3;  // read-side swizzle term

  f32x4 acc[4][4];
#pragma unroll
  for (int i = 0; i < 4; i++)
#pragma unroll
    for (int j = 0; j < 4; j++) acc[i][j] = f32x4{0.f, 0.f, 0.f, 0.f};

  // prologue: stage tile 0 into buffer 0
  gl2lds16(A + arow0 + cofs, &As[0][sA0 * 512]);
  gl2lds16(A + arow1 + cofs, &As[0][sA1 * 512]);
  gl2lds16(Bm + brow0 + cofs, &Bs[0][sA0 * 512]);
  gl2lds16(Bm + brow1 + cofs, &Bs[0][sA1 * 512]);

  int cur = 0;
  for (int k0 = 0; k0 < K; k0 += 32, cur ^= 1) {
    __syncthreads();  // drains staging loads for 'cur'; releases 'nxt' buffer
    int nxt = cur ^ 1;
    int k1 = k0 + 32;
    if (k1 < K) {
      gl2lds16(A + arow0 + k1 + cofs, &As[nxt][sA0 * 512]);
      gl2lds16(A + arow1 + k1 + cofs, &As[nxt][sA1 * 512]);
      gl2lds16(Bm + brow0 + k1 + cofs, &Bs[nxt][sA0 * 512]);
      gl2lds16(Bm + brow1 + k1 + cofs, &Bs[nxt][sA1 * 512]);
    }
    bf16x8 af[4], bf[4];
#pragma unroll
    for (int im = 0; im < 4; im++) af[im] = frag8(&As[cur][(wm + im * 16 + l15) * 32 + (g ^ rsw) * 8]);
#pragma unroll
    for (int jn = 0; jn < 4; jn++) bf[jn] = frag8(&Bs[cur][(wn + jn * 16 + l15) * 32 + (g ^ rsw) * 8]);
#pragma unroll
    for (int im = 0; im < 4; im++)
#pragma unroll
      for (int jn = 0; jn < 4; jn++)
        acc[im][jn] = __builtin_amdgcn_mfma_f32_16x16x32_bf16(af[im], bf[jn], acc[im][jn], 0, 0, 0);
  }

  const int row0 = bm * 128 + wm + g * 4;  // + im*16 + r
  const int col0 = bn * 128 + wn;          // + jn*16 + l15

  if (EPI == 0) {
#pragma unroll
    for (int jn = 0; jn < 4; jn++) {
      float bb = bias[col0 + jn * 16 + l15];
#pragma unroll
      for (int im = 0; im < 4; im++)
#pragma unroll
        for (int r = 0; r < 4; r++) {
          int row = row0 + im * 16 + r;
          Cout[row * N + col0 + jn * 16 + l15] = acc[im][jn][r] + bb;
        }
    }
  } else {
#pragma unroll
    for (int jn = 0; jn < 4; jn++) {
      float bb = bias[col0 + jn * 16 + l15];
#pragma unroll
      for (int im = 0; im < 4; im++)
#pragma unroll
        for (int r = 0; r < 4; r++) acc[im][jn][r] += bb;
    }
    const int sector = col0 >> 10;        // 0=q 1=k 2=v, wave-uniform
    const int h = (col0 & 1023) >> 6;     // wave-uniform head
    if (sector == 2) {
      // V^T scatter, vectorized along pos
#pragma unroll
      for (int jn = 0; jn < 4; jn++) {
        int d = jn * 16 + l15;
#pragma unroll
        for (int im = 0; im < 4; im++) {
          int row = row0 + im * 16;
          int b = row >> 11, pos = row & 2047;
          union { uint32_t u[2]; short4v s4; } pw;
          pw.u[0] = pk2bf(acc[im][jn][0], acc[im][jn][1]);
          pw.u[1] = pk2bf(acc[im][jn][2], acc[im][jn][3]);
          *(short4v*)&Vt[((b * 16 + h) * 64 + d) * 2048 + pos] = pw.s4;
        }
      }
    } else {
      short* dst = (sector == 0) ? Qb : Kb;
      const float scl = (sector == 0) ? 0.18033688011112042f : 1.0f;  // 0.125*log2(e) folded into Q
#pragma unroll
      for (int jn = 0; jn < 4; jn++) {
        int d = jn * 16 + l15;
        int j = d & 31;
#pragma unroll
        for (int im = 0; im < 4; im++)
#pragma unroll
          for (int r = 0; r < 4; r++) {
            int row = row0 + im * 16 + r;
            int b = row >> 11, pos = row & 2047;
            float c = cosT[pos * 32 + j];
            float s = sinT[pos * 32 + j];
            float xv = acc[im][jn][r];
            float xp = acc[im][jn ^ 2][r];         // partner d +/- 32 lives 2 n-tiles away
            float rot = (jn < 2) ? -xp : xp;       // d<32: -x[d+32]; d>=32: x[d-32]
            dst[((b * 16 + h) * 2048 + pos) * 64 + d] = f2bf((xv * c + rot * s) * scl);
          }
      }
    }
  }
}

// ---------- kernel 4: attention, no-max-sub exp2 softmax, double-buffered staging ----------
// grid (16 qtiles, 64 bh); block 256 = 4 waves; wave = 32 q x 64 kv tile; 32 kt iters.
// ONE barrier per iter: loads for kt+1 issue before compute of kt.
// Scores arrive pre-scaled (Q carries 0.125*log2e): p = exp2(s + maskf) unnormalized;
// row-sum l via MFMA with all-ones A fragment; single normalize in epilogue.
__global__ __launch_bounds__(256, 3)
void attn_k(const short* __restrict__ Qb, const short* __restrict__ Kb,
            const short* __restrict__ Vt, const float* __restrict__ maskf,
            short* __restrict__ attn) {
  __shared__ short Ks[2][64 * 64];  // [kv][d]  rows 128B = 8 chunks, swizzled
  __shared__ short Vs[2][64 * 64];  // [d][kv]  rows 128B = 8 chunks, swizzled
  __shared__ short Ps[4][32 * 64];  // per-wave [q][kv] rows 128B, swizzled
  const int tid = threadIdx.x, lane = tid & 63, w = tid >> 6;
  const int g = lane >> 4, l15 = lane & 15;
  const int sw = l15 & 7;
  const int qt = blockIdx.x, bh = blockIdx.y;
  const int b = bh >> 4, h = bh & 15;

  // Q B-fragments (resident): B[n=q=l15][k=d=g*8+j]
  bf16x8 aq[2][2];
#pragma unroll
  for (int qi = 0; qi < 2; qi++)
#pragma unroll
    for (int kc = 0; kc < 2; kc++) {
      int q = qt * 128 + w * 32 + qi * 16 + l15;
      aq[qi][kc] = *(const bf16x8*)(const void*)(Qb + (bh * 2048 + q) * 64 + kc * 32 + g * 8);
    }
  // all-ones A fragment for the l row-sum MFMA
  bf16x8 aone;
#pragma unroll
  for (int i = 0; i < 8; i++) aone[i] = (__bf16)1.0f;

  f32x4 o[4][2];   // O^T[d=jd*16+g*4+r][q=qi*16+l15]
#pragma unroll
  for (int jd = 0; jd < 4; jd++)
#pragma unroll
    for (int qi = 0; qi < 2; qi++) o[jd][qi] = f32x4{0.f, 0.f, 0.f, 0.f};
  f32x4 lacc[2] = {f32x4{0.f, 0.f, 0.f, 0.f}, f32x4{0.f, 0.f, 0.f, 0.f}};

  const float* mfp = maskf + b * 2048;
  const int r8 = lane >> 3;
  const int cst = (lane & 7) ^ r8;  // staging source chunk (swizzle)
  const int t0s = w * 4;            // this wave's first segment

  // prologue: stage tile 0 into buffer 0
#pragma unroll
  for (int t = 0; t < 4; t++) {
    int s = t0s + t;
    if (s < 8) gl2lds16(Kb + (bh * 2048 + s * 8 + r8) * 64 + cst * 8, &Ks[0][s * 512]);
    else       gl2lds16(Vt + (bh * 64 + (s - 8) * 8 + r8) * 2048 + cst * 8, &Vs[0][(s - 8) * 512]);
  }

  int cur = 0;
  for (int kt = 0; kt < 32; kt++, cur ^= 1) {
    const int kbase = kt * 64;
    __syncthreads();  // drains loads for 'cur'; releases 'nxt'
    int nxt = cur ^ 1;
    if (kt + 1 < 32) {
      const int nb = kbase + 64;
#pragma unroll
      for (int t = 0; t < 4; t++) {
        int s = t0s + t;
        if (s < 8) gl2lds16(Kb + (bh * 2048 + nb + s * 8 + r8) * 64 + cst * 8, &Ks[nxt][s * 512]);
        else       gl2lds16(Vt + (bh * 64 + (s - 8) * 8 + r8) * 2048 + nb + cst * 8, &Vs[nxt][(s - 8) * 512]);
      }
    }

    // S^T = K.Q^T with C initialized to maskf (mask add for free)
    f32x4 sv[4][2];
#pragma unroll
    for (int kvt = 0; kvt < 4; kvt++) {
      f32x4 mf = *(const f32x4*)(mfp + kbase + kvt * 16 + g * 4);
      sv[kvt][0] = mf; sv[kvt][1] = mf;
    }
#pragma unroll
    for (int kvt = 0; kvt < 4; kvt++)
#pragma unroll
      for (int kc = 0; kc < 2; kc++) {
        bf16x8 ak = frag8(&Ks[cur][(kvt * 16 + l15) * 64 + ((kc * 4 + g) ^ sw) * 8]);
        sv[kvt][0] = __builtin_amdgcn_mfma_f32_16x16x32_bf16(ak, aq[0][kc], sv[kvt][0], 0, 0, 0);
        sv[kvt][1] = __builtin_amdgcn_mfma_f32_16x16x32_bf16(ak, aq[1][kc], sv[kvt][1], 0, 0, 0);
      }

    // p = exp2(s), pack to bf16, write per-wave Ps (no barrier needed)
#pragma unroll
    for (int qi = 0; qi < 2; qi++)
#pragma unroll
      for (int kvt = 0; kvt < 4; kvt++) {
        union { uint32_t u[2]; short4v s4; } pw;
        pw.u[0] = pk2bf(EXP2(sv[kvt][qi][0]), EXP2(sv[kvt][qi][1]));
        pw.u[1] = pk2bf(EXP2(sv[kvt][qi][2]), EXP2(sv[kvt][qi][3]));
        *(short4v*)&Ps[w][(qi * 16 + l15) * 64 + ((2 * kvt + (g >> 1)) ^ sw) * 8 + (g & 1) * 4] = pw.s4;
      }

    // O^T += V.P^T ; l += 1.P^T
#pragma unroll
    for (int kc = 0; kc < 2; kc++) {
      bf16x8 av[4];
#pragma unroll
      for (int jd = 0; jd < 4; jd++)
        av[jd] = frag8(&Vs[cur][(jd * 16 + l15) * 64 + ((kc * 4 + g) ^ sw) * 8]);
#pragma unroll
      for (int qi = 0; qi < 2; qi++) {
        bf16x8 bp = frag8(&Ps[w][(qi * 16 + l15) * 64 + ((kc * 4 + g) ^ sw) * 8]);
#pragma unroll
        for (int jd = 0; jd < 4; jd++)
          o[jd][qi] = __builtin_amdgcn_mfma_f32_16x16x32_bf16(av[jd], bp, o[jd][qi], 0, 0, 0);
        lacc[qi] = __builtin_amdgcn_mfma_f32_16x16x32_bf16(aone, bp, lacc[qi], 0, 0, 0);
      }
    }
  }

  // epilogue: O^T / l -> bf16 attn[B,L,D], 8B stores
#pragma unroll
  for (int qi = 0; qi < 2; qi++) {
    float inv = 1.0f / lacc[qi][0];
    int q = qt * 128 + w * 32 + qi * 16 + l15;
#pragma unroll
    for (int jd = 0; jd < 4; jd++) {
      union { uint32_t u[2]; short4v s4; } pw;
      pw.u[0] = pk2bf(o[jd][qi][0] * inv, o[jd][qi][1] * inv);
      pw.u[1] = pk2bf(o[jd][qi][2] * inv, o[jd][qi][3] * inv);
      *(short4v*)&attn[(b * 2048 + q) * 1024 + h * 64 + jd * 16 + g * 4] = pw.s4;
    }
  }
}

// ---------- launch ----------
extern "C" void kernel_launch(void* const* d_in, const int* in_sizes, int n_in,
                              void* d_out, int out_size, void* d_ws, size_t ws_size,
                              hipStream_t stream) {
  const float* x = (const float*)d_in[0];
  const unsigned char* mask = (const unsigned char*)d_in[1];
  const float* W_qkv = (const float*)d_in[2];
  const float* b_qkv = (const float*)d_in[3];
  const float* W_out = (const float*)d_in[4];
  const float* b_out = (const float*)d_in[5];
  float* out = (float*)d_out;

  char* ws = (char*)d_ws;
  short* xb    = (short*)(ws + 0);          // 16,777,216 B
  short* wqkvb = (short*)(ws + 16777216);   //  6,291,456 B
  short* woutb = (short*)(ws + 23068672);   //  2,097,152 B
  float* cosT  = (float*)(ws + 25165824);   //    262,144 B
  float* sinT  = (float*)(ws + 25427968);   //    262,144 B
  short* Qb    = (short*)(ws + 25690112);   // 16,777,216 B  [bh][pos][64]
  short* Kb    = (short*)(ws + 42467328);   // 16,777,216 B  [bh][pos][64]
  short* Vtb   = (short*)(ws + 59244544);   // 16,777,216 B  [bh][64][pos]
  short* attnb = (short*)(ws + 76021760);   // 16,777,216 B  [B,L,D] bf16
  float* maskf = (float*)(ws + 92798976);   //     32,768 B

  convert3_k<<<12288, 256, 0, stream>>>(x, xb, 8388608, W_qkv, wqkvb, 3145728, W_out, woutb, 1048576);
  rope_tab_k<<<256, 256, 0, stream>>>(cosT, sinT, mask, maskf);
  gemm_bt_k<1><<<dim3(64, 24), 256, 0, stream>>>(xb, wqkvb, b_qkv, 3072, 1024,
                                                 nullptr, cosT, sinT, Qb, Kb, Vtb);
  attn_k<<<dim3(16, 64), 256, 0, stream>>>(Qb, Kb, Vtb, maskf, attnb);
  gemm_bt_k<0><<<dim3(64, 8), 256, 0, stream>>>(attnb, woutb, b_out, 1024, 1024,
                                                out, nullptr, nullptr, nullptr, nullptr, nullptr);
}

// Round 5
// 293.916 us; speedup vs baseline: 1.0353x; 1.0353x over previous
//
#include <hip/hip_runtime.h>
#include <stdint.h>

typedef __attribute__((ext_vector_type(8))) __bf16 bf16x8;
typedef __attribute__((ext_vector_type(4))) short short4v;
typedef __attribute__((ext_vector_type(4))) float f32x4;

#if __has_builtin(__builtin_amdgcn_exp2f)
#define EXP2(x) __builtin_amdgcn_exp2f(x)
#else
#define EXP2(x) exp2f(x)
#endif

// ---------- helpers ----------
__device__ __forceinline__ short f2bf(float f) {
  union { float f; uint32_t u; } v; v.f = f;
  uint32_t r = (v.u + 0x7fffu + ((v.u >> 16) & 1u)) >> 16;  // RNE
  return (short)(uint16_t)r;
}

// pack two fp32 -> two bf16 in one dword (RNE via hw bf16 cvt)
__device__ __forceinline__ uint32_t pk2bf(float a, float b) {
  union { __bf16 h; uint16_t u; } x, y;
  x.h = (__bf16)a; y.h = (__bf16)b;
  return (uint32_t)x.u | ((uint32_t)y.u << 16);
}

// async global->LDS, 16B per lane; lds base must be wave-uniform, HW writes lane i at base+16*i
__device__ __forceinline__ void gl2lds16(const void* g, const void* lds) {
  __builtin_amdgcn_global_load_lds(
      (const __attribute__((address_space(1))) void*)(uintptr_t)g,
      (__attribute__((address_space(3))) void*)(uint32_t)(uintptr_t)lds,
      16, 0, 0);
}

__device__ __forceinline__ bf16x8 frag8(const short* p) {
  return *(const bf16x8*)(const void*)p;
}

// ---------- kernel 1: fp32 -> bf16 for x, W_qkv, W_out ----------
__global__ void convert3_k(const float* __restrict__ s0, short* __restrict__ d0, int n0,
                           const float* __restrict__ s1, short* __restrict__ d1, int n1,
                           const float* __restrict__ s2, short* __restrict__ d2, int n2) {
  int i = blockIdx.x * blockDim.x + threadIdx.x;  // float4 units
  int t0 = n0 >> 2, t1 = t0 + (n1 >> 2), t2 = t1 + (n2 >> 2);
  const float* s; short* d; int off;
  if (i < t0) { s = s0; d = d0; off = i; }
  else if (i < t1) { s = s1; d = d1; off = i - t0; }
  else if (i < t2) { s = s2; d = d2; off = i - t1; }
  else return;
  float4 v = ((const float4*)s)[off];
  short4v o;
  o.x = f2bf(v.x); o.y = f2bf(v.y); o.z = f2bf(v.z); o.w = f2bf(v.w);
  *(short4v*)(d + off * 4) = o;
}

// ---------- kernel 2: RoPE tables [2048][32] + float mask table ----------
__global__ void rope_tab_k(float* __restrict__ cosT, float* __restrict__ sinT,
                           const unsigned char* __restrict__ mask, float* __restrict__ maskf) {
  int i = blockIdx.x * blockDim.x + threadIdx.x;  // 65536
  int pos = i >> 5, j = i & 31;
  float invf = exp2f(-(float)j * (8.965784284662087f / 32.0f));
  float ang = (float)pos * invf;
  float s, c;
  sincosf(ang, &s, &c);
  cosT[i] = c; sinT[i] = s;
  if (i < 8192) maskf[i] = mask[i] ? -1e30f : 0.0f;
}

// ---------- kernel 3/5: C[M,N] = A[M,K] * B[N,K]^T (+bias), bf16 in, MFMA ----------
// Double-buffered LDS staging, one barrier per k-iter.
// LDS rows are 64B = 4x16B chunks, XOR-swizzled to break 64B-stride bank aliasing.
// EPI==0: fp32 C + bias.  EPI==1: bias + RoPE + scatter Qb/Kb (bh,pos,d) and Vt (bh,d,pos).
// Q additionally scaled by 0.125*log2(e) so attention scores are ready for exp2.
template <int EPI>
__global__ __launch_bounds__(256, 3)
void gemm_bt_k(const short* __restrict__ A, const short* __restrict__ Bm,
               const float* __restrict__ bias, int N, int K,
               float* __restrict__ Cout,
               const float* __restrict__ cosT, const float* __restrict__ sinT,
               short* __restrict__ Qb, short* __restrict__ Kb, short* __restrict__ Vt) {
  __shared__ short As[2][128 * 32];
  __shared__ short Bs[2][128 * 32];
  const int tid = threadIdx.x;
  const int lane = tid & 63;
  const int w = tid >> 6;
  const int g = lane >> 4, l15 = lane & 15;
  const int wm = (w >> 1) * 64, wn = (w & 1) * 64;
  const int bm = blockIdx.x, bn = blockIdx.y;

  const int rseg = lane >> 2;
  const int cofs = ((lane & 3) ^ ((lane >> 3) & 3)) * 8;
  const int sA0 = w, sA1 = w + 4;
  const int arow0 = (bm * 128 + sA0 * 16 + rseg) * K;
  const int arow1 = (bm * 128 + sA1 * 16 + rseg) * K;
  const int brow0 = (bn * 128 + sA0 * 16 + rseg) * K;
  const int brow1 = (bn * 128 + sA1 * 16 + rseg) * K;

  const int rsw = (l15 >> 1) & 3;  // read-side swizzle term

  f32x4 acc[4][4];
#pragma unroll
  for (int i = 0; i < 4; i++)
#pragma unroll
    for (int j = 0; j < 4; j++) acc[i][j] = f32x4{0.f, 0.f, 0.f, 0.f};

  // prologue: stage tile 0 into buffer 0
  gl2lds16(A + arow0 + cofs, &As[0][sA0 * 512]);
  gl2lds16(A + arow1 + cofs, &As[0][sA1 * 512]);
  gl2lds16(Bm + brow0 + cofs, &Bs[0][sA0 * 512]);
  gl2lds16(Bm + brow1 + cofs, &Bs[0][sA1 * 512]);

  int cur = 0;
  for (int k0 = 0; k0 < K; k0 += 32, cur ^= 1) {
    __syncthreads();  // drains staging loads for 'cur'; releases 'nxt' buffer
    int nxt = cur ^ 1;
    int k1 = k0 + 32;
    if (k1 < K) {
      gl2lds16(A + arow0 + k1 + cofs, &As[nxt][sA0 * 512]);
      gl2lds16(A + arow1 + k1 + cofs, &As[nxt][sA1 * 512]);
      gl2lds16(Bm + brow0 + k1 + cofs, &Bs[nxt][sA0 * 512]);
      gl2lds16(Bm + brow1 + k1 + cofs, &Bs[nxt][sA1 * 512]);
    }
    bf16x8 af[4], bf[4];
#pragma unroll
    for (int im = 0; im < 4; im++) af[im] = frag8(&As[cur][(wm + im * 16 + l15) * 32 + (g ^ rsw) * 8]);
#pragma unroll
    for (int jn = 0; jn < 4; jn++) bf[jn] = frag8(&Bs[cur][(wn + jn * 16 + l15) * 32 + (g ^ rsw) * 8]);
#pragma unroll
    for (int im = 0; im < 4; im++)
#pragma unroll
      for (int jn = 0; jn < 4; jn++)
        acc[im][jn] = __builtin_amdgcn_mfma_f32_16x16x32_bf16(af[im], bf[jn], acc[im][jn], 0, 0, 0);
  }

  const int row0 = bm * 128 + wm + g * 4;  // + im*16 + r
  const int col0 = bn * 128 + wn;          // + jn*16 + l15

  if (EPI == 0) {
#pragma unroll
    for (int jn = 0; jn < 4; jn++) {
      float bb = bias[col0 + jn * 16 + l15];
#pragma unroll
      for (int im = 0; im < 4; im++)
#pragma unroll
        for (int r = 0; r < 4; r++) {
          int row = row0 + im * 16 + r;
          Cout[row * N + col0 + jn * 16 + l15] = acc[im][jn][r] + bb;
        }
    }
  } else {
#pragma unroll
    for (int jn = 0; jn < 4; jn++) {
      float bb = bias[col0 + jn * 16 + l15];
#pragma unroll
      for (int im = 0; im < 4; im++)
#pragma unroll
        for (int r = 0; r < 4; r++) acc[im][jn][r] += bb;
    }
    const int sector = col0 >> 10;        // 0=q 1=k 2=v, wave-uniform
    const int h = (col0 & 1023) >> 6;     // wave-uniform head
    if (sector == 2) {
      // V^T scatter, vectorized along pos
#pragma unroll
      for (int jn = 0; jn < 4; jn++) {
        int d = jn * 16 + l15;
#pragma unroll
        for (int im = 0; im < 4; im++) {
          int row = row0 + im * 16;
          int b = row >> 11, pos = row & 2047;
          union { uint32_t u[2]; short4v s4; } pw;
          pw.u[0] = pk2bf(acc[im][jn][0], acc[im][jn][1]);
          pw.u[1] = pk2bf(acc[im][jn][2], acc[im][jn][3]);
          *(short4v*)&Vt[((b * 16 + h) * 64 + d) * 2048 + pos] = pw.s4;
        }
      }
    } else {
      short* dst = (sector == 0) ? Qb : Kb;
      const float scl = (sector == 0) ? 0.18033688011112042f : 1.0f;  // 0.125*log2(e) folded into Q
#pragma unroll
      for (int jn = 0; jn < 4; jn++) {
        int d = jn * 16 + l15;
        int j = d & 31;
#pragma unroll
        for (int im = 0; im < 4; im++)
#pragma unroll
          for (int r = 0; r < 4; r++) {
            int row = row0 + im * 16 + r;
            int b = row >> 11, pos = row & 2047;
            float c = cosT[pos * 32 + j];
            float s = sinT[pos * 32 + j];
            float xv = acc[im][jn][r];
            float xp = acc[im][jn ^ 2][r];         // partner d +/- 32 lives 2 n-tiles away
            float rot = (jn < 2) ? -xp : xp;       // d<32: -x[d+32]; d>=32: x[d-32]
            dst[((b * 16 + h) * 2048 + pos) * 64 + d] = f2bf((xv * c + rot * s) * scl);
          }
      }
    }
  }
}

// ---------- kernel 4: attention ----------
// 128-thread blocks (2 waves), q=64/block (32/wave), kv-tile=32, dbuf staging, 64 iters.
// Grid 32x64 = 2048 blocks = exactly 8/CU at 20KB LDS -> 16 waves/CU, zero tail.
// Wave 0 stages K (4x1KB segs), wave 1 stages V^T; one barrier per iter.
// p = exp2(s + maskf) unnormalized (Q pre-scaled by 0.125*log2e); l via ones-MFMA.
__global__ __launch_bounds__(128, 4)
void attn_k(const short* __restrict__ Qb, const short* __restrict__ Kb,
            const short* __restrict__ Vt, const float* __restrict__ maskf,
            short* __restrict__ attn) {
  __shared__ short Ks[2][32 * 64];  // [kv][d]   rows 128B = 8 chunks, pos = c ^ (row&7)
  __shared__ short Vs[2][64 * 32];  // [d][kv]   rows  64B = 4 chunks, pos = c ^ ((row^(row>>2))&3)
  __shared__ short Ps[2][32 * 32];  // per-wave [q][kv] rows 64B, same 4-chunk swizzle
  const int tid = threadIdx.x, lane = tid & 63, w = tid >> 6;
  const int g = lane >> 4, l15 = lane & 15;
  const int swk = l15 & 7;                    // Ks read swizzle
  const int fv = (l15 ^ (l15 >> 2)) & 3;      // Vs/Ps read swizzle
  const int qt = blockIdx.x, bh = blockIdx.y;
  const int b = bh >> 4, h = bh & 15;

  // Q B-fragments (resident): B[n=q=l15][k=d=g*8+j]
  bf16x8 aq[2][2];
#pragma unroll
  for (int qi = 0; qi < 2; qi++)
#pragma unroll
    for (int kc = 0; kc < 2; kc++) {
      int q = qt * 64 + w * 32 + qi * 16 + l15;
      aq[qi][kc] = *(const bf16x8*)(const void*)(Qb + (bh * 2048 + q) * 64 + kc * 32 + g * 8);
    }
  // all-ones A fragment for the l row-sum MFMA
  bf16x8 aone;
#pragma unroll
  for (int i = 0; i < 8; i++) aone[i] = (__bf16)1.0f;

  f32x4 o[4][2];   // O^T[d=jd*16+g*4+r][q=qi*16+l15]
#pragma unroll
  for (int jd = 0; jd < 4; jd++)
#pragma unroll
    for (int qi = 0; qi < 2; qi++) o[jd][qi] = f32x4{0.f, 0.f, 0.f, 0.f};
  f32x4 lacc[2] = {f32x4{0.f, 0.f, 0.f, 0.f}, f32x4{0.f, 0.f, 0.f, 0.f}};

  const float* mfp = maskf + b * 2048;

  // staging address terms
  const int kr8 = lane >> 3;                 // K: row-in-seg
  const int kcst = (lane & 7) ^ kr8;         // K: source chunk (8-chunk swizzle)
  const int vrs = lane >> 2;                 // V: row-in-seg (d)
  const int vcs = (lane & 3) ^ ((vrs ^ (vrs >> 2)) & 3);  // V: source chunk (4-chunk swizzle)

  // prologue: stage tile 0 into buffer 0 (wave0: K, wave1: V)
  if (w == 0) {
#pragma unroll
    for (int s = 0; s < 4; s++)
      gl2lds16(Kb + (bh * 2048 + s * 8 + kr8) * 64 + kcst * 8, &Ks[0][s * 512]);
  } else {
#pragma unroll
    for (int s = 0; s < 4; s++)
      gl2lds16(Vt + (bh * 64 + s * 16 + vrs) * 2048 + vcs * 8, &Vs[0][s * 512]);
  }

  int cur = 0;
  for (int kt = 0; kt < 64; kt++, cur ^= 1) {
    const int kbase = kt * 32;
    __syncthreads();  // drains staging for 'cur'; releases 'nxt'
    int nxt = cur ^ 1;
    if (kt + 1 < 64) {
      const int nb = kbase + 32;
      if (w == 0) {
#pragma unroll
        for (int s = 0; s < 4; s++)
          gl2lds16(Kb + (bh * 2048 + nb + s * 8 + kr8) * 64 + kcst * 8, &Ks[nxt][s * 512]);
      } else {
#pragma unroll
        for (int s = 0; s < 4; s++)
          gl2lds16(Vt + (bh * 64 + s * 16 + vrs) * 2048 + nb + vcs * 8, &Vs[nxt][s * 512]);
      }
    }

    // S^T = K.Q^T with C initialized to maskf (mask add for free)
    f32x4 sv[2][2];
#pragma unroll
    for (int kvt = 0; kvt < 2; kvt++) {
      f32x4 mf = *(const f32x4*)(mfp + kbase + kvt * 16 + g * 4);
      sv[kvt][0] = mf; sv[kvt][1] = mf;
    }
#pragma unroll
    for (int kvt = 0; kvt < 2; kvt++)
#pragma unroll
      for (int kc = 0; kc < 2; kc++) {
        bf16x8 ak = frag8(&Ks[cur][(kvt * 16 + l15) * 64 + ((kc * 4 + g) ^ swk) * 8]);
        sv[kvt][0] = __builtin_amdgcn_mfma_f32_16x16x32_bf16(ak, aq[0][kc], sv[kvt][0], 0, 0, 0);
        sv[kvt][1] = __builtin_amdgcn_mfma_f32_16x16x32_bf16(ak, aq[1][kc], sv[kvt][1], 0, 0, 0);
      }

    // p = exp2(s), pack to bf16, write per-wave Ps (no barrier needed: own region)
#pragma unroll
    for (int qi = 0; qi < 2; qi++)
#pragma unroll
      for (int kvt = 0; kvt < 2; kvt++) {
        union { uint32_t u[2]; short4v s4; } pw;
        pw.u[0] = pk2bf(EXP2(sv[kvt][qi][0]), EXP2(sv[kvt][qi][1]));
        pw.u[1] = pk2bf(EXP2(sv[kvt][qi][2]), EXP2(sv[kvt][qi][3]));
        *(short4v*)&Ps[w][(qi * 16 + l15) * 32 + (((kvt * 2 + (g >> 1)) ^ fv) * 8) + (g & 1) * 4] = pw.s4;
      }

    // O^T += V.P^T ; l += 1.P^T   (K-dim = 32 -> one kc chunk)
    {
      bf16x8 av[4];
#pragma unroll
      for (int jd = 0; jd < 4; jd++)
        av[jd] = frag8(&Vs[cur][(jd * 16 + l15) * 32 + (g ^ fv) * 8]);
#pragma unroll
      for (int qi = 0; qi < 2; qi++) {
        bf16x8 bp = frag8(&Ps[w][(qi * 16 + l15) * 32 + (g ^ fv) * 8]);
#pragma unroll
        for (int jd = 0; jd < 4; jd++)
          o[jd][qi] = __builtin_amdgcn_mfma_f32_16x16x32_bf16(av[jd], bp, o[jd][qi], 0, 0, 0);
        lacc[qi] = __builtin_amdgcn_mfma_f32_16x16x32_bf16(aone, bp, lacc[qi], 0, 0, 0);
      }
    }
  }

  // epilogue: O^T / l -> bf16 attn[B,L,D], 8B stores
#pragma unroll
  for (int qi = 0; qi < 2; qi++) {
    float inv = 1.0f / lacc[qi][0];
    int q = qt * 64 + w * 32 + qi * 16 + l15;
#pragma unroll
    for (int jd = 0; jd < 4; jd++) {
      union { uint32_t u[2]; short4v s4; } pw;
      pw.u[0] = pk2bf(o[jd][qi][0] * inv, o[jd][qi][1] * inv);
      pw.u[1] = pk2bf(o[jd][qi][2] * inv, o[jd][qi][3] * inv);
      *(short4v*)&attn[(b * 2048 + q) * 1024 + h * 64 + jd * 16 + g * 4] = pw.s4;
    }
  }
}

// ---------- launch ----------
extern "C" void kernel_launch(void* const* d_in, const int* in_sizes, int n_in,
                              void* d_out, int out_size, void* d_ws, size_t ws_size,
                              hipStream_t stream) {
  const float* x = (const float*)d_in[0];
  const unsigned char* mask = (const unsigned char*)d_in[1];
  const float* W_qkv = (const float*)d_in[2];
  const float* b_qkv = (const float*)d_in[3];
  const float* W_out = (const float*)d_in[4];
  const float* b_out = (const float*)d_in[5];
  float* out = (float*)d_out;

  char* ws = (char*)d_ws;
  short* xb    = (short*)(ws + 0);          // 16,777,216 B
  short* wqkvb = (short*)(ws + 16777216);   //  6,291,456 B
  short* woutb = (short*)(ws + 23068672);   //  2,097,152 B
  float* cosT  = (float*)(ws + 25165824);   //    262,144 B
  float* sinT  = (float*)(ws + 25427968);   //    262,144 B
  short* Qb    = (short*)(ws + 25690112);   // 16,777,216 B  [bh][pos][64]
  short* Kb    = (short*)(ws + 42467328);   // 16,777,216 B  [bh][pos][64]
  short* Vtb   = (short*)(ws + 59244544);   // 16,777,216 B  [bh][64][pos]
  short* attnb = (short*)(ws + 76021760);   // 16,777,216 B  [B,L,D] bf16
  float* maskf = (float*)(ws + 92798976);   //     32,768 B

  convert3_k<<<12288, 256, 0, stream>>>(x, xb, 8388608, W_qkv, wqkvb, 3145728, W_out, woutb, 1048576);
  rope_tab_k<<<256, 256, 0, stream>>>(cosT, sinT, mask, maskf);
  gemm_bt_k<1><<<dim3(64, 24), 256, 0, stream>>>(xb, wqkvb, b_qkv, 3072, 1024,
                                                 nullptr, cosT, sinT, Qb, Kb, Vtb);
  attn_k<<<dim3(32, 64), 128, 0, stream>>>(Qb, Kb, Vtb, maskf, attnb);
  gemm_bt_k<0><<<dim3(64, 8), 256, 0, stream>>>(attnb, woutb, b_out, 1024, 1024,
                                                out, nullptr, nullptr, nullptr, nullptr, nullptr);
}